// Round 1
// baseline (104.943 us; speedup 1.0000x reference)
//
#include <hip/hip_runtime.h>

typedef short  sv8 __attribute__((ext_vector_type(8)));   // 8 bf16 (4 VGPRs)
typedef float  fv16 __attribute__((ext_vector_type(16))); // MFMA C/D
typedef unsigned int uv4 __attribute__((ext_vector_type(4)));
typedef unsigned int uv2 __attribute__((ext_vector_type(2)));
typedef unsigned int uint32;
typedef unsigned short ushort16;

#define NF      10
#define CIN     64
#define NTOT    8192              // T*H*W
#define HW      1024
#define FPAD    16                // feature dim padded for MFMA K
#define MSPLIT  16                // m-splits (partials -> reduce kernel)
#define MCHUNK  (NTOT / MSPLIT)   // 512 m per block
#define PSTRIDE 16                // f-stride of partial buffer

// Native gfx950 shape: v_mfma_f32_32x32x16_bf16 (measured 2382 TF, ~8cyc).
//   C/D: col=lane&31, row=(reg&3)+8*(reg>>2)+4*(lane>>5)   [measured m74/m101]
//   A:   i=lane&31,   k=8*(lane>>5)+j  (j=0..7)
//   B:   j=lane&31,   k=8*(lane>>5)+jj
#define MFMA32(a, b, c) __builtin_amdgcn_mfma_f32_32x32x16_bf16((a), (b), (c), 0, 0, 0)

static __device__ inline ushort16 f32_to_bf16_rne(float x) {
    uint32 u = __builtin_bit_cast(uint32, x);
    u = (u + 0x7fffu + ((u >> 16) & 1u)) >> 16;
    return (ushort16)u;
}

// ---------------------------------------------------------------------------
// Stage 1: projections -> bf16 workspace.
//   qb[n][16], kb[n][16] row-major bf16 (f-pad zeroed) — serve as 32x32x16
//   B/A frags directly: lane reads row (base+col), bytes [h*16, h*16+16).
//   vfrag: V in PV A-frag order. Per 32-m tile tau, two 1KB frags (fs=0,1):
//     byte addr = tau*2048 + fs*1024 + (h*32+f)*16, holding 8 bf16 =
//     v[f][m = 32*tau + fs*16 + 8h + j], j=0..7. f>=10 slots zero.
// grid (NTOT/64, 2), block 64.
// ---------------------------------------------------------------------------
__global__ __launch_bounds__(64) void qkv_kernel(
    const float* __restrict__ in1, const float* __restrict__ in2,
    const float* __restrict__ w1, const float* __restrict__ b1,
    const float* __restrict__ w2, const float* __restrict__ b2,
    const float* __restrict__ w3, const float* __restrict__ b3,
    ushort16* __restrict__ qb, ushort16* __restrict__ kb,
    ushort16* __restrict__ vfrag)
{
    __shared__ ushort16 lvs[64][FPAD];                 // v staging, 2 KB

    const int tid = threadIdx.x;
    const int n  = blockIdx.x * 64 + tid;
    const int t  = n >> 10;
    const int hw = n & 1023;

    if (blockIdx.y == 0) {
        const float* p = in1 + (size_t)t * (CIN * HW) + hw;
        float a[CIN];
#pragma unroll
        for (int c = 0; c < CIN; ++c) a[c] = p[c * HW];   // 64 loads in flight

        float aq[NF], av[NF];
#pragma unroll
        for (int f = 0; f < NF; ++f) { aq[f] = b1[f]; av[f] = b3[f]; }
#pragma unroll
        for (int c = 0; c < CIN; ++c) {
#pragma unroll
            for (int f = 0; f < NF; ++f) {
                aq[f] = fmaf(w1[f * CIN + c], a[c], aq[f]);
                av[f] = fmaf(w3[f * CIN + c], a[c], av[f]);
            }
        }
        ushort16 row[FPAD];
#pragma unroll
        for (int f = 0; f < NF; ++f) row[f] = f32_to_bf16_rne(aq[f]);
#pragma unroll
        for (int f = NF; f < FPAD; ++f) row[f] = 0;       // K-pad MUST be zero
        ushort16* dq = qb + (size_t)n * FPAD;
        ((uint4*)dq)[0] = ((const uint4*)row)[0];
        ((uint4*)dq)[1] = ((const uint4*)row)[1];

        // v: stage to LDS, then emit PV A-fragments
#pragma unroll
        for (int f = 0; f < NF; ++f) lvs[tid][f] = f32_to_bf16_rne(av[f]);
        __syncthreads();
        const int l  = tid & 31;                          // f-slot
        const int tl = tid >> 5;                          // local 32-m tile
        char* base = (char*)vfrag + ((size_t)(blockIdx.x * 2 + tl)) * 2048;
#pragma unroll
        for (int fs = 0; fs < 2; ++fs) {
#pragma unroll
            for (int hh = 0; hh < 2; ++hh) {
                ushort16 buf[8];
#pragma unroll
                for (int j = 0; j < 8; ++j)
                    buf[j] = (l < NF) ? lvs[32 * tl + fs * 16 + 8 * hh + j][l]
                                      : (ushort16)0;
                *(uint4*)(base + fs * 1024 + (hh * 32 + l) * 16) =
                    *(const uint4*)buf;
            }
        }
    } else {
        const float* p = in2 + (size_t)t * (CIN * HW) + hw;
        float a[CIN];
#pragma unroll
        for (int c = 0; c < CIN; ++c) a[c] = p[c * HW];

        float ak[NF];
#pragma unroll
        for (int f = 0; f < NF; ++f) ak[f] = b2[f];
#pragma unroll
        for (int c = 0; c < CIN; ++c) {
#pragma unroll
            for (int f = 0; f < NF; ++f) ak[f] = fmaf(w2[f * CIN + c], a[c], ak[f]);
        }
        ushort16 row[FPAD];
#pragma unroll
        for (int f = 0; f < NF; ++f) row[f] = f32_to_bf16_rne(ak[f]);
#pragma unroll
        for (int f = NF; f < FPAD; ++f) row[f] = 0;
        ushort16* dk = kb + (size_t)n * FPAD;
        ((uint4*)dk)[0] = ((const uint4*)row)[0];
        ((uint4*)dk)[1] = ((const uint4*)row)[1];
    }
}

// ---------------------------------------------------------------------------
// Stage 2: native 32x32x16 MFMA attention. Per 32m-step:
//   S = mfma32(Kfrag, Qfrag)          -> 32m x 32n scores (1 MFMA)
//   relu + pack to bf16 pairs p[0..7] -> cross-half exchange via
//   v_permlane32_swap_b32 (VALU pipe; replaces 8 ds_bpermute + 16 cndmask)
//   acc1 += mfma32(Vfrag_lo, B1) ; acc2 += mfma32(Vfrag_hi, B2)
// grid (64, MSPLIT) = 1024 blocks, block 256 (4 waves: one 32-n tile each).
// ---------------------------------------------------------------------------
__global__ __launch_bounds__(256) void attn_mfma_kernel(
    const ushort16* __restrict__ qb, const ushort16* __restrict__ kb,
    const ushort16* __restrict__ vfrag, float* __restrict__ pws)
{
    const int lane = threadIdx.x & 63;
    const int wid  = threadIdx.x >> 6;
    const int col  = lane & 31;                        // n_local / m-row
    const int h    = lane >> 5;                        // k-half
    const int n0   = (blockIdx.x * 4 + wid) * 32;
    const int m0   = blockIdx.y * MCHUNK;

    // Q B-frag (loop-invariant): qb[n0+col], bytes [16h, 16h+16)
    const uint4 qraw = *(const uint4*)((const char*)qb + (size_t)(n0 + col) * 32 + h * 16);
    const sv8 qf = __builtin_bit_cast(sv8, qraw);

    const char* kbase = (const char*)kb + (size_t)(m0 + col) * 32 + h * 16;   // +1024/step
    const char* vbase = (const char*)vfrag + (size_t)(m0 >> 5) * 2048 + lane * 16; // +2048/step

    fv16 zerov, acc1, acc2;
#pragma unroll
    for (int i = 0; i < 16; ++i) { zerov[i] = 0.f; acc1[i] = 0.f; acc2[i] = 0.f; }

    uint4 kf = *(const uint4*)kbase;
    uint4 v1 = *(const uint4*)vbase;
    uint4 v2 = *(const uint4*)(vbase + 1024);

    for (int s = 0; s < MCHUNK / 32; ++s) {
        // unconditional prefetch (last-step over-read lands in ws, unused).
        // offsets (1024/2048/3072) fold into the 13-bit global_load immediate;
        // bases are bumped at loop end (2 pointer adds vs per-load 64b math).
        uint4 kf_n = *(const uint4*)(kbase + 1024);
        uint4 v1_n = *(const uint4*)(vbase + 2048);
        uint4 v2_n = *(const uint4*)(vbase + 3072);

        fv16 S = MFMA32(__builtin_bit_cast(sv8, kf), qf, zerov);

        // relu + truncate-pack: p[i] = (bf16(S[2i]) , bf16(S[2i+1]))
        // reg r -> m = (r&3) + 8*(r>>2) + 4h
        uint32 p[8];
#pragma unroll
        for (int i = 0; i < 8; ++i) {
            float e0 = fmaxf(S[2 * i], 0.f);
            float e1 = fmaxf(S[2 * i + 1], 0.f);
            p[i] = __builtin_amdgcn_perm(__builtin_bit_cast(uint32, e1),
                                         __builtin_bit_cast(uint32, e0), 0x07060302u);
        }

        // Cross-half exchange, one instruction per output pair:
        //   r[0] = [own lanes0-31            | partner(lane-32) lanes0-31 ]
        //   r[1] = [partner(lane+32) lanes32-63 | own lanes32-63          ]
        // which is exactly the old  h ? sw : p  selection for B1/B2:
        //   B1 (k=m_local 0..15):  x,y from (p0,p1)/(p2,p3) swap fronts,
        //                          z,w from the returned tails.
        uv2 r0 = __builtin_amdgcn_permlane32_swap(p[0], p[2], false, false);
        uv2 r1 = __builtin_amdgcn_permlane32_swap(p[1], p[3], false, false);
        uv2 r2 = __builtin_amdgcn_permlane32_swap(p[4], p[6], false, false);
        uv2 r3 = __builtin_amdgcn_permlane32_swap(p[5], p[7], false, false);

        uv4 b1 = { r0[0], r1[0], r0[1], r1[1] };
        uv4 b2 = { r2[0], r3[0], r2[1], r3[1] };

        acc1 = MFMA32(__builtin_bit_cast(sv8, v1), __builtin_bit_cast(sv8, b1), acc1);
        acc2 = MFMA32(__builtin_bit_cast(sv8, v2), __builtin_bit_cast(sv8, b2), acc2);

        kf = kf_n; v1 = v1_n; v2 = v2_n;
        kbase += 1024; vbase += 2048;
    }

    // Epilogue: D[f][n]: f = (r&3)+8*(r>>2)+4h, n = n0+col
    const int n = n0 + col;
#pragma unroll
    for (int r = 0; r < 16; ++r) {
        int f = (r & 3) + 8 * (r >> 2) + 4 * h;
        if (f < NF)
            pws[((size_t)blockIdx.y * PSTRIDE + f) * NTOT + n] = acc1[r] + acc2[r];
    }
}

// ---------------------------------------------------------------------------
// Stage 3: sum MSPLIT partials, write out[t][f][h][w]. grid 320 x 256.
// ---------------------------------------------------------------------------
__global__ __launch_bounds__(256) void reduce_kernel(
    const float* __restrict__ pws, float* __restrict__ out)
{
    const int gid = blockIdx.x * 256 + threadIdx.x;    // 0 .. NF*NTOT-1
    const int f = gid >> 13;                           // / NTOT
    const int n = gid & (NTOT - 1);
    float s = 0.f;
#pragma unroll
    for (int y = 0; y < MSPLIT; ++y)
        s += pws[((size_t)y * PSTRIDE + f) * NTOT + n];
    const int t = n >> 10, hw = n & 1023;
    out[(size_t)t * (NF * HW) + f * HW + hw] = s;
}

extern "C" void kernel_launch(void* const* d_in, const int* in_sizes, int n_in,
                              void* d_out, int out_size, void* d_ws, size_t ws_size,
                              hipStream_t stream)
{
    const float* in1 = (const float*)d_in[0];
    const float* in2 = (const float*)d_in[1];
    const float* w1  = (const float*)d_in[2];
    const float* b1  = (const float*)d_in[3];
    const float* w2  = (const float*)d_in[4];
    const float* b2  = (const float*)d_in[5];
    const float* w3  = (const float*)d_in[6];
    const float* b3  = (const float*)d_in[7];

    // ws layout: qb (256K) | kb (256K) | vfrag (512K) | pws (8 MB fp32)
    ushort16* qb    = (ushort16*)d_ws;
    ushort16* kb    = qb + (size_t)NTOT * FPAD;
    ushort16* vfrag = kb + (size_t)NTOT * FPAD;
    float*    pws   = (float*)((char*)vfrag + 512 * 1024);
    float*    out   = (float*)d_out;

    qkv_kernel<<<dim3(NTOT / 64, 2), 64, 0, stream>>>(
        in1, in2, w1, b1, w2, b2, w3, b3, qb, kb, vfrag);

    attn_mfma_kernel<<<dim3(64, MSPLIT), 256, 0, stream>>>(qb, kb, vfrag, pws);

    reduce_kernel<<<dim3(NF * NTOT / 256), 256, 0, stream>>>(pws, out);
}